// Round 15
// baseline (3261.994 us; speedup 1.0000x reference)
//
#include <hip/hip_runtime.h>
#include <hip/hip_fp16.h>
#include <math.h>

#define NG 100
#define ND 200
#define NLINE 500
#define NB 300
#define NW 50
#define NS 128
#define NX 500
#define CVIOL 20000.0f
#define NITERS 600
#define PITERS 50
#define NUPAD_MAX 304

#define NC   13
#define NUC  208

// workspace layout (float offsets)
#define OFF_HSPB 0          // packed f16 reg-load layout: 8*208*32 u32 = 53248
#define OFF_HST  114688     // 304*512 fp32
#define OFF_B    270336     // BuPk: 304*152 u32 = 46208
#define OFF_HWT  360336     // 50*500
#define OFF_QC   385336     // 128*500
#define OFF_QD   449336     // 128*500
#define OFF_RUP  513336
#define OFF_RDN  513436
#define OFF_FUP  513536
#define OFF_FDN  514036
#define OFF_QE   514536
#define OFF_STEP 514664
#define OFF_NU   514665
#define OFF_NUP  514666
#define OFF_NUC  514667     // 208 = reg kernel, 0 = fallback
#define OFF_BUS  514668
#define OFF_BUSW 514968
#define OFF_UBUS 515018
#define OFF_C2U  515322
#define OFF_CUS  515622
#define OFF_CUL  515927

typedef _Float16 half2v __attribute__((ext_vector_type(2)));
union f16pair { unsigned int u; _Float16 h[2]; half2v v; };
__device__ __forceinline__ float h2lo(unsigned int x){ f16pair p; p.u = x; return (float)p.h[0]; }
__device__ __forceinline__ float h2hi(unsigned int x){ f16pair p; p.u = x; return (float)p.h[1]; }
__device__ __forceinline__ half2v h2v(unsigned int x){ f16pair p; p.u = x; return p.v; }

#if defined(__has_builtin)
#if __has_builtin(__builtin_amdgcn_fdot2)
#define HAVE_FDOT2 1
#endif
#endif

// ---------------------------------------------------------------- K1: precompute + unique-bus build (LDS serial)
__global__ __launch_bounds__(512) void k_pre(
    const float* __restrict__ p_da, const float* __restrict__ r_up_hat,
    const float* __restrict__ r_down_hat, const float* __restrict__ fup_hat,
    const float* __restrict__ fdn_hat, const float* __restrict__ w_err,
    const float* __restrict__ Pmax, const float* __restrict__ nG,
    const float* __restrict__ nL, const float* __restrict__ nW, float* ws) {
  __shared__ int busL[NB];
  __shared__ int uidxL[NB];
  __shared__ int cntL[NUPAD_MAX];
  __shared__ int ubusL[NUPAD_MAX];
  __shared__ int c2uL[NB];
  __shared__ int cusL[NUPAD_MAX + 1];
  __shared__ int culL[NB];
  const int t = threadIdx.x;
  int* busW = (int*)(ws + OFF_BUSW);
  if (t < NG) {
    int bf = 0;
    for (int b = 0; b < NB; ++b) if (nG[b*NG + t] > 0.5f) bf = b;
    busL[t] = bf;
    ws[OFF_RUP + t] = fmaxf(fminf(r_up_hat[t], Pmax[t] - p_da[t]), 0.f);
    ws[OFF_RDN + t] = fmaxf(fminf(r_down_hat[t], p_da[t]), 0.f);
  }
  if (t < ND) {
    int bf = 0;
    for (int b = 0; b < NB; ++b) if (nL[b*ND + t] > 0.5f) bf = b;
    busL[NG + t] = bf;
  }
  if (t < NW) {
    int bf = 0;
    for (int b = 0; b < NB; ++b) if (nW[b*NW + t] > 0.5f) bf = b;
    busW[t] = bf;
  }
  if (t < NLINE) {
    ws[OFF_FUP + t] = fmaxf(fup_hat[t], 0.f);
    ws[OFF_FDN + t] = fmaxf(fdn_hat[t], 0.f);
  }
  if (t < NS) {
    float s = 0.f;
    for (int w = 0; w < NW; ++w) s += w_err[t*NW + w];
    ws[OFF_QE + t] = -s;
  }
  __syncthreads();
  if (t == 0) {
    for (int b = 0; b < NB; ++b) uidxL[b] = -1;
    int nu = 0;
    for (int c = 0; c < NB; ++c) {
      const int b = busL[c];
      if (uidxL[b] < 0) { uidxL[b] = nu; ubusL[nu] = b; nu++; }
      c2uL[c] = uidxL[b];
    }
    for (int u = nu; u < NUPAD_MAX; ++u) ubusL[u] = 0;
    ((int*)(ws + OFF_NU))[0]  = nu;
    ((int*)(ws + OFF_NUP))[0] = (nu + 31) & ~31;
    ((int*)(ws + OFF_NUC))[0] = (nu <= NUC) ? NUC : 0;
    for (int u = 0; u < NUPAD_MAX; ++u) cntL[u] = 0;
    for (int c = 0; c < NB; ++c) cntL[c2uL[c]]++;
    int acc = 0;
    for (int u = 0; u < nu; ++u) { cusL[u] = acc; acc += cntL[u]; cntL[u] = cusL[u]; }
    for (int u = nu; u <= NUPAD_MAX; ++u) { if (u < NUPAD_MAX + 1) cusL[u] = acc; }
    for (int c = 0; c < NB; ++c) culL[cntL[c2uL[c]]++] = c;
  }
  __syncthreads();
  if (t < NUPAD_MAX) ((int*)(ws + OFF_UBUS))[t] = ubusL[t];
  if (t < NUPAD_MAX + 1) ((int*)(ws + OFF_CUS))[t] = cusL[t];
  if (t < NB) {
    ((int*)(ws + OFF_C2U))[t] = c2uL[t];
    ((int*)(ws + OFF_CUL))[t] = culL[t];
  }
}

// ---------------------------------------------------------------- K2: gather HST (fp32) + HSPB (packed f16)
__global__ __launch_bounds__(512) void k_buildH(const float* __restrict__ PTDF, float* ws) {
  const int l = blockIdx.x;
  const int t = threadIdx.x;
  const int NU   = ((const int*)(ws + OFF_NU))[0];
  const int NUCr = ((const int*)(ws + OFF_NUC))[0];
  const int* ubus = (const int*)(ws + OFF_UBUS);
  const int* busW = (const int*)(ws + OFF_BUSW);
  unsigned short* hb = (unsigned short*)(ws + OFF_HSPB);
  if (t < NUPAD_MAX) {
    const float val = (t < NU) ? PTDF[l*NB + ubus[t]] : 0.f;
    ws[OFF_HST + t*512 + l] = val;
    if (l == 0) {
      for (int ll = NLINE; ll < 512; ++ll) ws[OFF_HST + t*512 + ll] = 0.f;
    }
    if (NUCr > 0 && t < NUCr) {
      const int jp = l >> 6, half = (l >> 5) & 1, rg = l & 31;
      const unsigned short bv = __half_as_ushort(__float2half(val));
      hb[((((jp*NUC + t) << 5) + rg) << 1) + half] = bv;
      if (l == 0) {
        for (int rr = 20; rr < 32; ++rr)
          hb[((((7*NUC + t) << 5) + rr) << 1) + 1] = 0;
      }
    }
  } else if (t < NUPAD_MAX + NW) {
    const int w = t - NUPAD_MAX;
    ws[OFF_HWT + w*NLINE + l] = PTDF[l*NB + busW[w]];
  }
}

// ---------------------------------------------------------------- K3: BuPk[e][pair] = f16x2 of col dots (304x152)
__global__ __launch_bounds__(192) void k_buildB(float* ws) {
  const int e = blockIdx.x;          // 0..303
  const int j = threadIdx.x;
  if (j >= 152) return;
  const float* __restrict__ re  = ws + OFF_HST + e*512;
  const float* __restrict__ rf0 = ws + OFF_HST + (2*j)*512;
  const float* __restrict__ rf1 = rf0 + 512;
  float a0 = 0.f, a1 = 0.f;
  #pragma unroll 4
  for (int l = 0; l < NLINE; ++l) {
    const float rv = re[l];
    a0 = fmaf(rv, rf0[l], a0);
    a1 = fmaf(rv, rf1[l], a1);
  }
  const unsigned int pk = (unsigned int)__half_as_ushort(__float2half(a0)) |
                          ((unsigned int)__half_as_ushort(__float2half(a1)) << 16);
  ((unsigned int*)(ws + OFF_B))[e*152 + j] = pk;
}

// ---------------------------------------------------------------- K4: power iteration on compressed Bu -> step
__global__ __launch_bounds__(512) void k_power(float* ws) {
  __shared__ unsigned int BuL[208*105];
  __shared__ __align__(16) float v[512];
  __shared__ float q3[NB];
  __shared__ __align__(16) float busq[NUPAD_MAX];
  __shared__ float gq[416];
  __shared__ int c2uL[NB], cusL[NUPAD_MAX + 1], culL[NB];
  __shared__ float sEs, sSs;
  const int t = threadIdx.x;
  const int NUCr = ((const int*)(ws + OFF_NUC))[0];
  const bool small = (NUCr == NUC);
  const unsigned int* __restrict__ BuPk = (const unsigned int*)(ws + OFF_B);
  if (small) {
    for (int i = t; i < 208*104; i += 512)
      BuL[(i/104)*105 + (i%104)] = BuPk[(i/104)*152 + (i%104)];
  }
  if (t < NB) { c2uL[t] = ((const int*)(ws + OFF_C2U))[t]; culL[t] = ((const int*)(ws + OFF_CUL))[t]; }
  if (t < NUPAD_MAX + 1) cusL[t] = ((const int*)(ws + OFF_CUS))[t];
  v[t] = (t < NX) ? (1.0f / sqrtf(500.0f)) : 0.f;
  __syncthreads();
  float s_last = 1.f;
  for (int it = 0; it < PITERS; ++it) {
    if (t < NG) q3[t] = v[t] - v[t + NG] - v[t + 2*NG];
    else if (t < NB) q3[t] = v[t + 200];
    __syncthreads();
    if (t < NUPAD_MAX) {
      float a = 0.f;
      const int ke = cusL[t + 1];
      for (int kk = cusL[t]; kk < ke; ++kk) {
        const int c = culL[kk];
        a += (c < NG) ? (q3[c] - q3[NG + c] - q3[2*NG + c]) : q3[200 + c];
      }
      busq[t] = a;
    }
    __syncthreads();
    if (small) {
      if (t < 416) {
        const int u = (t < 208) ? t : t - 208;
        const int p0 = (t < 208) ? 0 : 52;
        float a = 0.f;
        const unsigned int* row = BuL + u*105;
        #pragma unroll 4
        for (int p = p0; p < p0 + 52; ++p) {
          const unsigned int bu = row[p];
          const float2 bq = *(const float2*)&busq[2*p];
          a = fmaf(h2lo(bu), bq.x, fmaf(h2hi(bu), bq.y, a));
        }
        gq[t] = a;
      }
    } else {
      if (t < NUPAD_MAX) {
        float a = 0.f;
        const unsigned int* row = BuPk + t*152;
        for (int p = 0; p < 152; ++p) {
          const unsigned int bu = row[p];
          const float2 bq = *(const float2*)&busq[2*p];
          a = fmaf(h2lo(bu), bq.x, fmaf(h2hi(bu), bq.y, a));
        }
        gq[t] = a;
      }
    }
    if (t >= 448) {
      const int lane = t - 448;
      float e = 0.f;
      for (int idx = lane; idx < NB; idx += 64) e += q3[idx];
      for (int o = 32; o; o >>= 1) e += __shfl_down(e, o);
      if (lane == 0) sEs = e;
    }
    __syncthreads();
    if (t < NX) {
      const float E = sEs;
      const int ci = (t < NG) ? t : ((t < 2*NG) ? t - NG : ((t < NB) ? t - 2*NG : t - 200));
      const int ux = c2uL[ci];
      const float bq = small ? (gq[ux] + gq[208 + ux]) : gq[ux];
      float nv;
      if (t < NG)        nv = v[t] + 2.f*bq + E;
      else if (t < 2*NG) nv = v[t] - 2.f*bq - E;
      else if (t < NB)   nv = -2.f*bq - E;
      else               nv = 2.f*bq + E;
      v[t] = nv;
    }
    __syncthreads();
    if (t < 64) {
      float p = 0.f;
      for (int k = t; k < NX; k += 64) p += v[k]*v[k];
      for (int o = 32; o; o >>= 1) p += __shfl_down(p, o);
      if (t == 0) sSs = p;
    }
    __syncthreads();
    const float sn = sqrtf(sSs);
    if (t < NX) v[t] /= sn;
    s_last = sn;
    __syncthreads();
  }
  if (t == 0) ws[OFF_STEP] = 0.9f / sqrtf(s_last);
}

// ---------------------------------------------------------------- K5: qC,qD per scenario
__global__ __launch_bounds__(512) void k_buildq(const float* __restrict__ w_err, float* ws) {
  const int s = blockIdx.x;
  const int t = threadIdx.x;
  __shared__ float wsh[NW];
  if (t < NW) wsh[t] = w_err[s*NW + t];
  __syncthreads();
  if (t < NLINE) {
    float wh = 0.f;
    #pragma unroll
    for (int w = 0; w < NW; ++w)
      wh = fmaf(wsh[w], ws[OFF_HWT + w*NLINE + t], wh);
    ws[OFF_QC + s*NLINE + t] = ws[OFF_FUP + t] - wh;
    ws[OFF_QD + s*NLINE + t] = ws[OFF_FDN + t] + wh;
  }
}

// ---------------------------------------------------------------- macro machinery (params named hv/k: no member capture)
#define ROWKR(M,jp) M(jp,0) M(jp,1) M(jp,2) M(jp,3) M(jp,4) M(jp,5) M(jp,6) M(jp,7)
#define JPLIST(M) M(0) M(1) M(2) M(3) M(4) M(5) M(6) M(7)
#define KLIST(M)  M(0) M(1) M(2) M(3) M(4) M(5) M(6) M(7) M(8) M(9) M(10) M(11) M(12)

#define DECLH(jp,k) unsigned int hr##jp##_##k;
#define DECLROW(jp) ROWKR(DECLH,jp) DECLH(jp,12)
#define LDH(jp,k)   hr##jp##_##k = hpu[((((jp)*NUC) + cbase + (k)) << 5) + rg];
#define LDROW(jp)   ROWKR(LDH,jp) LDH(jp,12)

#define ACCD(k)     float acc##k = 0.f;

#ifdef HAVE_FDOT2
#define DOTA(hv, k) acc##k = __builtin_amdgcn_fdot2(h2v(hv), uh2, acc##k, false);
#else
#define DOTA(hv, k) { const unsigned int hcu_ = (hv); \
                      acc##k = fmaf(h2lo(hcu_), uu0, fmaf(h2hi(hcu_), uu1, acc##k)); }
#endif

#define PHA(jp)     { const unsigned int upk_ = u_pk[rg + ((jp) << 5)]; \
                      const half2v uh2 = h2v(upk_); (void)uh2; \
                      const float uu0 = h2lo(upk_), uu1 = h2hi(upk_); \
                      (void)uu0; (void)uu1; \
                      DOTA(hr##jp##_0, 0) DOTA(hr##jp##_1, 1) DOTA(hr##jp##_2, 2) DOTA(hr##jp##_3, 3) \
                      DOTA(hr##jp##_4, 4) DOTA(hr##jp##_5, 5) DOTA(hr##jp##_6, 6) DOTA(hr##jp##_7, 7) \
                      const uint4 q4_ = hx4[((jp) << 9) + t]; \
                      DOTA(q4_.x, 8) DOTA(q4_.y, 9) DOTA(q4_.z, 10) DOTA(q4_.w, 11) \
                      DOTA(hr##jp##_12, 12) }

#define TS16(k)     acc##k += __shfl_xor(acc##k, 16);
#define TRED(j)     tv##j += __shfl_xor(tv##j, 8); tv##j += __shfl_xor(tv##j, 4); \
                    tv##j += __shfl_xor(tv##j, 2); tv##j += __shfl_xor(tv##j, 1);

#define BRD(k)      const unsigned int _lo##k = __builtin_amdgcn_readlane(bzu, (k)); \
                    const unsigned int _hi##k = __builtin_amdgcn_readlane(bzu, 32 + (k)); \
                    const float b##k = __uint_as_float((t & 32) ? _hi##k : _lo##k);

#define CMC(hv, k)  { const unsigned int hcu_ = (hv); \
                      fx = fmaf(h2lo(hcu_), b##k, fx); fy = fmaf(h2hi(hcu_), b##k, fy); }
#define PHC(jp)     { float fx = 0.f, fy = 0.f; \
                      CMC(hr##jp##_0, 0) CMC(hr##jp##_1, 1) CMC(hr##jp##_2, 2) CMC(hr##jp##_3, 3) \
                      CMC(hr##jp##_4, 4) CMC(hr##jp##_5, 5) CMC(hr##jp##_6, 6) CMC(hr##jp##_7, 7) \
                      const uint4 q4_ = hx4[((jp) << 9) + t]; \
                      CMC(q4_.x, 8) CMC(q4_.y, 9) CMC(q4_.z, 10) CMC(q4_.w, 11) \
                      CMC(hr##jp##_12, 12) \
                      fx += __shfl_xor(fx, 32); fy += __shfl_xor(fy, 32); \
                      if ((t & 32) == 0) fpart2[w][rg + ((jp) << 5)] = make_float2(fx, fy); }

// ---------------------------------------------------------------- K6: PDHG v3 (f16 tile, 9 reg cols + dot2)
__global__ __launch_bounds__(512) void k_pdhg_reg(const float* __restrict__ ws,
                                                  float* __restrict__ out) {
  const int NUCr = ((const int*)(ws + OFF_NUC))[0];
  if (NUCr != NUC) return;

  __shared__ uint4 hx4[8*512];             // cols 8..11, [jp][cg*32+rg] : 64 KB
  __shared__ unsigned int u_pk[256];       // half2 pairs (u[l], u[l+32])
  __shared__ __align__(16) float x_s[512], z_s[512];
  __shared__ float ts[NUC];
  __shared__ __align__(16) float2 fpart2[8][256];
  __shared__ __align__(16) float2 qC2[256], qD2[256], yC2[256], yD2[256];
  __shared__ float yA[NG], yB[NG], qA[NG], qB[NG];
  __shared__ float sYE[1];
  __shared__ int c2u_s[NB], cus_s[NUPAD_MAX + 1], cul_s[NB];

  const int t = threadIdx.x;
  const int s = blockIdx.x;
  const int rg = t & 31, cg = t >> 5, w = t >> 6;
  const int cbase = cg * NC;
  const float step = ws[OFF_STEP];
  const float qE = ws[OFF_QE + s];

  // ---- init
  x_s[t] = 0.f; z_s[t] = 0.f;
  if (t < 256) {
    const int l = (t & 31) + ((t >> 5) << 6);
    const float qc0 = (l < NLINE)      ? ws[OFF_QC + s*NLINE + l]      : 0.f;
    const float qc1 = (l + 32 < NLINE) ? ws[OFF_QC + s*NLINE + l + 32] : 0.f;
    const float qd0 = (l < NLINE)      ? ws[OFF_QD + s*NLINE + l]      : 0.f;
    const float qd1 = (l + 32 < NLINE) ? ws[OFF_QD + s*NLINE + l + 32] : 0.f;
    qC2[t] = make_float2(qc0, qc1); qD2[t] = make_float2(qd0, qd1);
    yC2[t] = make_float2(0.f, 0.f); yD2[t] = make_float2(0.f, 0.f);
    u_pk[t] = 0u;
  }
  if (t < NG) { yA[t] = 0.f; yB[t] = 0.f; qA[t] = ws[OFF_RUP + t]; qB[t] = ws[OFF_RDN + t]; }
  if (t < NB) {
    c2u_s[t] = ((const int*)(ws + OFF_C2U))[t];
    cul_s[t] = ((const int*)(ws + OFF_CUL))[t];
  }
  if (t < NUPAD_MAX + 1) cus_s[t] = ((const int*)(ws + OFF_CUS))[t];
  if (t == 0) sYE[0] = 0.f;

  // ---- load tile: cols 0..7 + 12 named regs, cols 8..11 LDS
  JPLIST(DECLROW)
  {
    const unsigned int* __restrict__ hpu = (const unsigned int*)(ws + OFF_HSPB);
    JPLIST(LDROW)
    #pragma unroll
    for (int jp = 0; jp < 8; ++jp) {
      hx4[(jp << 9) + t] = make_uint4(
        hpu[((jp*NUC + cbase +  8) << 5) + rg],
        hpu[((jp*NUC + cbase +  9) << 5) + rg],
        hpu[((jp*NUC + cbase + 10) << 5) + rg],
        hpu[((jp*NUC + cbase + 11) << 5) + rg]);
    }
  }
  __syncthreads();

  for (int it = 0; it < NITERS; ++it) {
    // ---- Phase A: ts = Hs^T u (dot2), split-tree reduction over 32 lanes
    {
      KLIST(ACCD)
      JPLIST(PHA)
      KLIST(TS16)
      const bool up16 = (t & 16) != 0;
      float tv0 = up16 ? acc7  : acc0;
      float tv1 = up16 ? acc8  : acc1;
      float tv2 = up16 ? acc9  : acc2;
      float tv3 = up16 ? acc10 : acc3;
      float tv4 = up16 ? acc11 : acc4;
      float tv5 = up16 ? acc12 : acc5;
      float tv6 = acc6;
      TRED(0) TRED(1) TRED(2) TRED(3) TRED(4) TRED(5) TRED(6)
      const int jsel = t & 15;
      float wv = tv0;
      wv = (jsel == 1) ? tv1 : wv; wv = (jsel == 2) ? tv2 : wv;
      wv = (jsel == 3) ? tv3 : wv; wv = (jsel == 4) ? tv4 : wv;
      wv = (jsel == 5) ? tv5 : wv; wv = (jsel == 6) ? tv6 : wv;
      const int kout = up16 ? (jsel + 7) : jsel;
      if (up16 ? (jsel < 6) : (jsel < 7)) ts[cbase + kout] = wv;
    }
    __syncthreads();

    // ---- Phase B: x-update
    if (t < NX) {
      const int cc = (t < NB) ? (t % NG) : (t - 200);
      const float tg = ts[c2u_s[cc]];
      const float yE = sYE[0];
      float yK;
      if (t < NG)        yK = yA[t] + tg + yE;
      else if (t < 2*NG) yK = yB[t - NG] - tg - yE;
      else if (t < NB)   yK = -tg - yE;
      else               yK = tg + yE;
      const float cj = (t < 2*NG) ? 0.f : CVIOL;
      const float xo = x_s[t];
      const float x1 = fmaxf(xo - step*(cj + yK), 0.f);
      z_s[t] = 2.f*x1 - xo;
      x_s[t] = x1;
    }
    __syncthreads();

    // ---- Phase C: lane-parallel busz + readlane broadcast, then f partials
    {
      float bz = 0.f;
      if (rg < NC) {
        const int c = cbase + rg;
        const int ke = cus_s[c + 1];
        float a = 0.f;
        for (int kk = cus_s[c]; kk < ke; ++kk) {
          const int comp = cul_s[kk];
          a += (comp < NG) ? (z_s[comp] - z_s[NG + comp] - z_s[2*NG + comp])
                           : z_s[200 + comp];
        }
        bz = a;
      }
      const unsigned int bzu = __float_as_uint(bz);
      KLIST(BRD)
      JPLIST(PHC)
    }
    __syncthreads();

    // ---- Phase D: paired y-update + u; yA/yB; E (wave 7)
    if (t < 256) {
      float2 cv = make_float2(0.f, 0.f);
      #pragma unroll
      for (int g = 0; g < 8; ++g) { const float2 fp = fpart2[g][t]; cv.x += fp.x; cv.y += fp.y; }
      const float2 qc = qC2[t], qd = qD2[t], yc = yC2[t], yd = yD2[t];
      const float cy0 = fmaxf(yc.x + step*( cv.x - qc.x), 0.f);
      const float dy0 = fmaxf(yd.x + step*(-cv.x - qd.x), 0.f);
      const float cy1 = fmaxf(yc.y + step*( cv.y - qc.y), 0.f);
      const float dy1 = fmaxf(yd.y + step*(-cv.y - qd.y), 0.f);
      yC2[t] = make_float2(cy0, cy1); yD2[t] = make_float2(dy0, dy1);
      const unsigned int upk =
          (unsigned int)__half_as_ushort(__float2half(cy0 - dy0)) |
          ((unsigned int)__half_as_ushort(__float2half(cy1 - dy1)) << 16);
      u_pk[t] = upk;
    }
    if (t >= 256 && t < 456) {
      const int g = t - 256;
      if (g < NG) yA[g] = fmaxf(yA[g] + step*(z_s[g] - qA[g]), 0.f);
      else { const int gb = g - NG; yB[gb] = fmaxf(yB[gb] + step*(z_s[g] - qB[gb]), 0.f); }
    }
    if (t >= 448) {
      const int lane = t - 448;
      float e = 0.f;
      #pragma unroll
      for (int m = 0; m < 8; ++m) {
        const int idx = lane + (m << 6);
        const float zv = z_s[idx];                // z_s[500..511] stay 0
        e += (idx < NG || idx >= NB) ? zv : -zv;
      }
      e += __shfl_xor(e, 32); e += __shfl_xor(e, 16); e += __shfl_xor(e, 8);
      e += __shfl_xor(e, 4);  e += __shfl_xor(e, 2);  e += __shfl_xor(e, 1);
      if (t == 511) sYE[0] += step*(e - qE);
    }
    __syncthreads();
  }

  // ---- cost = CVIOL * sum(x[200:500])
  if (t < 64) {
    float p = 0.f;
    for (int k = 200 + t; k < NX; k += 64) p += x_s[k];
    for (int o = 32; o; o >>= 1) p += __shfl_down(p, o);
    if (t == 0) out[s] = CVIOL * p;
  }
}

// ---------------------------------------------------------------- K6fb: streaming fallback (NU > 208)
__global__ __launch_bounds__(1024) void k_pdhg_fb(const float* __restrict__ ws,
                                                  float* __restrict__ out) {
  const int NUCr = ((const int*)(ws + OFF_NUC))[0];
  if (NUCr != 0) return;
  const int NUPr = ((const int*)(ws + OFF_NUP))[0];

  __shared__ float u_s[512], x_s[512], z_s[512], cv_s[512];
  __shared__ float ts[NUPAD_MAX], busz[NUPAD_MAX];
  __shared__ float yC[NLINE], yD[NLINE], qC[NLINE], qD[NLINE];
  __shared__ float yA[NG], yB[NG], qA[NG], qB[NG];
  __shared__ float sE[1], sYE[1];
  __shared__ int c2u_s[NB], cus_s[NUPAD_MAX + 1], cul_s[NB];

  const int t = threadIdx.x;
  const int s = blockIdx.x;
  const float step = ws[OFF_STEP];
  const float qE = ws[OFF_QE + s];
  const float* __restrict__ HST = ws + OFF_HST;

  if (t < 512) { u_s[t] = 0.f; x_s[t] = 0.f; z_s[t] = 0.f; }
  if (t < NLINE) {
    yC[t] = 0.f; yD[t] = 0.f;
    qC[t] = ws[OFF_QC + s*NLINE + t];
    qD[t] = ws[OFF_QD + s*NLINE + t];
  }
  if (t < NG) { yA[t] = 0.f; yB[t] = 0.f; qA[t] = ws[OFF_RUP + t]; qB[t] = ws[OFF_RDN + t]; }
  if (t < NB) {
    c2u_s[t] = ((const int*)(ws + OFF_C2U))[t];
    cul_s[t] = ((const int*)(ws + OFF_CUL))[t];
  }
  if (t < NUPAD_MAX + 1) cus_s[t] = ((const int*)(ws + OFF_CUS))[t];
  if (t == 0) { sE[0] = 0.f; sYE[0] = 0.f; }
  __syncthreads();

  const int w = t >> 6, lane = t & 63;

  for (int it = 0; it < NITERS; ++it) {
    for (int c = w; c < NUPr; c += 16) {
      float a = 0.f;
      #pragma unroll
      for (int m = 0; m < 8; ++m) { const int l = lane + (m << 6); a = fmaf(HST[c*512 + l], u_s[l], a); }
      a += __shfl_xor(a, 32); a += __shfl_xor(a, 16); a += __shfl_xor(a, 8);
      a += __shfl_xor(a, 4);  a += __shfl_xor(a, 2);  a += __shfl_xor(a, 1);
      if (lane == 0) ts[c] = a;
    }
    __syncthreads();
    if (t < NX) {
      const int cc = (t < NB) ? (t % NG) : (t - 200);
      const float tg = ts[c2u_s[cc]];
      const float yE = sYE[0];
      float yK;
      if (t < NG)        yK = yA[t] + tg + yE;
      else if (t < 2*NG) yK = yB[t - NG] - tg - yE;
      else if (t < NB)   yK = -tg - yE;
      else               yK = tg + yE;
      const float cj = (t < 2*NG) ? 0.f : CVIOL;
      const float xo = x_s[t];
      const float x1 = fmaxf(xo - step*(cj + yK), 0.f);
      z_s[t] = 2.f*x1 - xo;
      x_s[t] = x1;
    }
    __syncthreads();
    if (t < NUPr) {
      float a = 0.f;
      const int k0 = cus_s[t], k1 = cus_s[t + 1];
      for (int k = k0; k < k1; ++k) {
        const int c = cul_s[k];
        a += (c < NG) ? (z_s[c] - z_s[NG + c] - z_s[2*NG + c]) : z_s[200 + c];
      }
      busz[t] = a;
    } else if (t >= 768 && t < 832) {
      const int ln = t - 768;
      float e = 0.f;
      for (int idx = ln; idx < NX; idx += 64) {
        const float zv = z_s[idx];
        e += (idx < NG || idx >= NB) ? zv : -zv;
      }
      e += __shfl_xor(e, 32); e += __shfl_xor(e, 16); e += __shfl_xor(e, 8);
      e += __shfl_xor(e, 4);  e += __shfl_xor(e, 2);  e += __shfl_xor(e, 1);
      if (ln == 0) sE[0] = e;
    }
    __syncthreads();
    if (t < 512) {
      float a = 0.f;
      for (int c = 0; c < NUPr; ++c) a = fmaf(HST[c*512 + t], busz[c], a);
      cv_s[t] = a;
    }
    __syncthreads();
    if (t < NLINE) {
      const float cv = cv_s[t];
      const float cy = fmaxf(yC[t] + step*( cv - qC[t]), 0.f);
      const float dy = fmaxf(yD[t] + step*(-cv - qD[t]), 0.f);
      yC[t] = cy; yD[t] = dy; u_s[t] = cy - dy;
    } else if (t >= 512 && t < 612) {
      const int g = t - 512;
      yA[g] = fmaxf(yA[g] + step*(z_s[g] - qA[g]), 0.f);
    } else if (t >= 612 && t < 712) {
      const int g = t - 612;
      yB[g] = fmaxf(yB[g] + step*(z_s[NG + g] - qB[g]), 0.f);
    } else if (t == 1023) {
      sYE[0] += step*(sE[0] - qE);
    }
    __syncthreads();
  }
  if (t < 64) {
    float p = 0.f;
    for (int k = 200 + t; k < NX; k += 64) p += x_s[k];
    for (int o = 32; o; o >>= 1) p += __shfl_down(p, o);
    if (t == 0) out[s] = CVIOL * p;
  }
}

extern "C" void kernel_launch(void* const* d_in, const int* in_sizes, int n_in,
                              void* d_out, int out_size, void* d_ws, size_t ws_size,
                              hipStream_t stream) {
  (void)in_sizes; (void)n_in; (void)out_size; (void)ws_size;
  const float* p_da      = (const float*)d_in[0];
  const float* r_up_hat  = (const float*)d_in[1];
  const float* r_dn_hat  = (const float*)d_in[2];
  const float* fup_hat   = (const float*)d_in[3];
  const float* fdn_hat   = (const float*)d_in[4];
  const float* w_err     = (const float*)d_in[5];
  const float* Pmax      = (const float*)d_in[6];
  const float* PTDF      = (const float*)d_in[7];
  const float* nG        = (const float*)d_in[8];
  const float* nL        = (const float*)d_in[9];
  const float* nW        = (const float*)d_in[10];
  float* ws  = (float*)d_ws;
  float* out = (float*)d_out;

  hipLaunchKernelGGL(k_pre,    dim3(1),   dim3(512),  0, stream,
                     p_da, r_up_hat, r_dn_hat, fup_hat, fdn_hat, w_err, Pmax, nG, nL, nW, ws);
  hipLaunchKernelGGL(k_buildH, dim3(500), dim3(512),  0, stream, PTDF, ws);
  hipLaunchKernelGGL(k_buildB, dim3(304), dim3(192),  0, stream, ws);
  hipLaunchKernelGGL(k_power,  dim3(1),   dim3(512),  0, stream, ws);
  hipLaunchKernelGGL(k_buildq, dim3(128), dim3(512),  0, stream, w_err, ws);
  hipLaunchKernelGGL(k_pdhg_reg, dim3(128), dim3(512), 0, stream, ws, out);
  hipLaunchKernelGGL(k_pdhg_fb, dim3(128), dim3(1024), 0, stream, ws, out);
}

// Round 16
// 2625.452 us; speedup vs baseline: 1.2425x; 1.2425x over previous
//
#include <hip/hip_runtime.h>
#include <hip/hip_fp16.h>
#include <math.h>

#define NG 100
#define ND 200
#define NLINE 500
#define NB 300
#define NW 50
#define NS 128
#define NX 500
#define CVIOL 20000.0f
#define NITERS 600
#define PITERS 50
#define NUPAD_MAX 304

#define NC   13
#define NUC  208

// workspace layout (float offsets)
#define OFF_HSPB 0          // packed f16 reg-load layout: 8*208*32 u32 = 53248
#define OFF_HST  114688     // 304*512 fp32
#define OFF_B    270336     // BuPk: 304*152 u32 = 46208
#define OFF_HWT  360336     // 50*500
#define OFF_QC   385336     // 128*500
#define OFF_QD   449336     // 128*500
#define OFF_RUP  513336
#define OFF_RDN  513436
#define OFF_FUP  513536
#define OFF_FDN  514036
#define OFF_QE   514536
#define OFF_STEP 514664
#define OFF_NU   514665
#define OFF_NUP  514666
#define OFF_NUC  514667     // 208 = reg kernel, 0 = fallback
#define OFF_BUS  514668
#define OFF_BUSW 514968
#define OFF_UBUS 515018
#define OFF_C2U  515322
#define OFF_CUS  515622
#define OFF_CUL  515927

typedef _Float16 half2v __attribute__((ext_vector_type(2)));
union f16pair { unsigned int u; _Float16 h[2]; half2v v; };
__device__ __forceinline__ float h2lo(unsigned int x){ f16pair p; p.u = x; return (float)p.h[0]; }
__device__ __forceinline__ float h2hi(unsigned int x){ f16pair p; p.u = x; return (float)p.h[1]; }
__device__ __forceinline__ half2v h2v(unsigned int x){ f16pair p; p.u = x; return p.v; }

#if defined(__has_builtin)
#if __has_builtin(__builtin_amdgcn_fdot2)
#define HAVE_FDOT2 1
#endif
#endif

// ---------------------------------------------------------------- K1: precompute + unique-bus build (LDS serial)
__global__ __launch_bounds__(512) void k_pre(
    const float* __restrict__ p_da, const float* __restrict__ r_up_hat,
    const float* __restrict__ r_down_hat, const float* __restrict__ fup_hat,
    const float* __restrict__ fdn_hat, const float* __restrict__ w_err,
    const float* __restrict__ Pmax, const float* __restrict__ nG,
    const float* __restrict__ nL, const float* __restrict__ nW, float* ws) {
  __shared__ int busL[NB];
  __shared__ int uidxL[NB];
  __shared__ int cntL[NUPAD_MAX];
  __shared__ int ubusL[NUPAD_MAX];
  __shared__ int c2uL[NB];
  __shared__ int cusL[NUPAD_MAX + 1];
  __shared__ int culL[NB];
  const int t = threadIdx.x;
  int* busW = (int*)(ws + OFF_BUSW);
  if (t < NG) {
    int bf = 0;
    for (int b = 0; b < NB; ++b) if (nG[b*NG + t] > 0.5f) bf = b;
    busL[t] = bf;
    ws[OFF_RUP + t] = fmaxf(fminf(r_up_hat[t], Pmax[t] - p_da[t]), 0.f);
    ws[OFF_RDN + t] = fmaxf(fminf(r_down_hat[t], p_da[t]), 0.f);
  }
  if (t < ND) {
    int bf = 0;
    for (int b = 0; b < NB; ++b) if (nL[b*ND + t] > 0.5f) bf = b;
    busL[NG + t] = bf;
  }
  if (t < NW) {
    int bf = 0;
    for (int b = 0; b < NB; ++b) if (nW[b*NW + t] > 0.5f) bf = b;
    busW[t] = bf;
  }
  if (t < NLINE) {
    ws[OFF_FUP + t] = fmaxf(fup_hat[t], 0.f);
    ws[OFF_FDN + t] = fmaxf(fdn_hat[t], 0.f);
  }
  if (t < NS) {
    float s = 0.f;
    for (int w = 0; w < NW; ++w) s += w_err[t*NW + w];
    ws[OFF_QE + t] = -s;
  }
  __syncthreads();
  if (t == 0) {
    for (int b = 0; b < NB; ++b) uidxL[b] = -1;
    int nu = 0;
    for (int c = 0; c < NB; ++c) {
      const int b = busL[c];
      if (uidxL[b] < 0) { uidxL[b] = nu; ubusL[nu] = b; nu++; }
      c2uL[c] = uidxL[b];
    }
    for (int u = nu; u < NUPAD_MAX; ++u) ubusL[u] = 0;
    ((int*)(ws + OFF_NU))[0]  = nu;
    ((int*)(ws + OFF_NUP))[0] = (nu + 31) & ~31;
    ((int*)(ws + OFF_NUC))[0] = (nu <= NUC) ? NUC : 0;
    for (int u = 0; u < NUPAD_MAX; ++u) cntL[u] = 0;
    for (int c = 0; c < NB; ++c) cntL[c2uL[c]]++;
    int acc = 0;
    for (int u = 0; u < nu; ++u) { cusL[u] = acc; acc += cntL[u]; cntL[u] = cusL[u]; }
    for (int u = nu; u <= NUPAD_MAX; ++u) { if (u < NUPAD_MAX + 1) cusL[u] = acc; }
    for (int c = 0; c < NB; ++c) culL[cntL[c2uL[c]]++] = c;
  }
  __syncthreads();
  if (t < NUPAD_MAX) ((int*)(ws + OFF_UBUS))[t] = ubusL[t];
  if (t < NUPAD_MAX + 1) ((int*)(ws + OFF_CUS))[t] = cusL[t];
  if (t < NB) {
    ((int*)(ws + OFF_C2U))[t] = c2uL[t];
    ((int*)(ws + OFF_CUL))[t] = culL[t];
  }
}

// ---------------------------------------------------------------- K2: gather HST (fp32) + HSPB (packed f16)
__global__ __launch_bounds__(512) void k_buildH(const float* __restrict__ PTDF, float* ws) {
  const int l = blockIdx.x;
  const int t = threadIdx.x;
  const int NU   = ((const int*)(ws + OFF_NU))[0];
  const int NUCr = ((const int*)(ws + OFF_NUC))[0];
  const int* ubus = (const int*)(ws + OFF_UBUS);
  const int* busW = (const int*)(ws + OFF_BUSW);
  unsigned short* hb = (unsigned short*)(ws + OFF_HSPB);
  if (t < NUPAD_MAX) {
    const float val = (t < NU) ? PTDF[l*NB + ubus[t]] : 0.f;
    ws[OFF_HST + t*512 + l] = val;
    if (l == 0) {
      for (int ll = NLINE; ll < 512; ++ll) ws[OFF_HST + t*512 + ll] = 0.f;
    }
    if (NUCr > 0 && t < NUCr) {
      const int jp = l >> 6, half = (l >> 5) & 1, rg = l & 31;
      const unsigned short bv = __half_as_ushort(__float2half(val));
      hb[((((jp*NUC + t) << 5) + rg) << 1) + half] = bv;
      if (l == 0) {
        for (int rr = 20; rr < 32; ++rr)
          hb[((((7*NUC + t) << 5) + rr) << 1) + 1] = 0;
      }
    }
  } else if (t < NUPAD_MAX + NW) {
    const int w = t - NUPAD_MAX;
    ws[OFF_HWT + w*NLINE + l] = PTDF[l*NB + busW[w]];
  }
}

// ---------------------------------------------------------------- K3: BuPk[e][pair] = f16x2 of col dots (304x152)
__global__ __launch_bounds__(192) void k_buildB(float* ws) {
  const int e = blockIdx.x;          // 0..303
  const int j = threadIdx.x;
  if (j >= 152) return;
  const float* __restrict__ re  = ws + OFF_HST + e*512;
  const float* __restrict__ rf0 = ws + OFF_HST + (2*j)*512;
  const float* __restrict__ rf1 = rf0 + 512;
  float a0 = 0.f, a1 = 0.f;
  #pragma unroll 4
  for (int l = 0; l < NLINE; ++l) {
    const float rv = re[l];
    a0 = fmaf(rv, rf0[l], a0);
    a1 = fmaf(rv, rf1[l], a1);
  }
  const unsigned int pk = (unsigned int)__half_as_ushort(__float2half(a0)) |
                          ((unsigned int)__half_as_ushort(__float2half(a1)) << 16);
  ((unsigned int*)(ws + OFF_B))[e*152 + j] = pk;
}

// ---------------------------------------------------------------- K4: power iteration on compressed Bu -> step
__global__ __launch_bounds__(512) void k_power(float* ws) {
  __shared__ unsigned int BuL[208*105];
  __shared__ __align__(16) float v[512];
  __shared__ float q3[NB];
  __shared__ __align__(16) float busq[NUPAD_MAX];
  __shared__ float gq[416];
  __shared__ int c2uL[NB], cusL[NUPAD_MAX + 1], culL[NB];
  __shared__ float sEs, sSs;
  const int t = threadIdx.x;
  const int NUCr = ((const int*)(ws + OFF_NUC))[0];
  const bool small = (NUCr == NUC);
  const unsigned int* __restrict__ BuPk = (const unsigned int*)(ws + OFF_B);
  if (small) {
    for (int i = t; i < 208*104; i += 512)
      BuL[(i/104)*105 + (i%104)] = BuPk[(i/104)*152 + (i%104)];
  }
  if (t < NB) { c2uL[t] = ((const int*)(ws + OFF_C2U))[t]; culL[t] = ((const int*)(ws + OFF_CUL))[t]; }
  if (t < NUPAD_MAX + 1) cusL[t] = ((const int*)(ws + OFF_CUS))[t];
  v[t] = (t < NX) ? (1.0f / sqrtf(500.0f)) : 0.f;
  __syncthreads();
  float s_last = 1.f;
  for (int it = 0; it < PITERS; ++it) {
    if (t < NG) q3[t] = v[t] - v[t + NG] - v[t + 2*NG];
    else if (t < NB) q3[t] = v[t + 200];
    __syncthreads();
    if (t < NUPAD_MAX) {
      float a = 0.f;
      const int ke = cusL[t + 1];
      for (int kk = cusL[t]; kk < ke; ++kk) {
        const int c = culL[kk];
        a += (c < NG) ? (q3[c] - q3[NG + c] - q3[2*NG + c]) : q3[200 + c];
      }
      busq[t] = a;
    }
    __syncthreads();
    if (small) {
      if (t < 416) {
        const int u = (t < 208) ? t : t - 208;
        const int p0 = (t < 208) ? 0 : 52;
        float a = 0.f;
        const unsigned int* row = BuL + u*105;
        #pragma unroll 4
        for (int p = p0; p < p0 + 52; ++p) {
          const unsigned int bu = row[p];
          const float2 bq = *(const float2*)&busq[2*p];
          a = fmaf(h2lo(bu), bq.x, fmaf(h2hi(bu), bq.y, a));
        }
        gq[t] = a;
      }
    } else {
      if (t < NUPAD_MAX) {
        float a = 0.f;
        const unsigned int* row = BuPk + t*152;
        for (int p = 0; p < 152; ++p) {
          const unsigned int bu = row[p];
          const float2 bq = *(const float2*)&busq[2*p];
          a = fmaf(h2lo(bu), bq.x, fmaf(h2hi(bu), bq.y, a));
        }
        gq[t] = a;
      }
    }
    if (t >= 448) {
      const int lane = t - 448;
      float e = 0.f;
      for (int idx = lane; idx < NB; idx += 64) e += q3[idx];
      for (int o = 32; o; o >>= 1) e += __shfl_down(e, o);
      if (lane == 0) sEs = e;
    }
    __syncthreads();
    if (t < NX) {
      const float E = sEs;
      const int ci = (t < NG) ? t : ((t < 2*NG) ? t - NG : ((t < NB) ? t - 2*NG : t - 200));
      const int ux = c2uL[ci];
      const float bq = small ? (gq[ux] + gq[208 + ux]) : gq[ux];
      float nv;
      if (t < NG)        nv = v[t] + 2.f*bq + E;
      else if (t < 2*NG) nv = v[t] - 2.f*bq - E;
      else if (t < NB)   nv = -2.f*bq - E;
      else               nv = 2.f*bq + E;
      v[t] = nv;
    }
    __syncthreads();
    if (t < 64) {
      float p = 0.f;
      for (int k = t; k < NX; k += 64) p += v[k]*v[k];
      for (int o = 32; o; o >>= 1) p += __shfl_down(p, o);
      if (t == 0) sSs = p;
    }
    __syncthreads();
    const float sn = sqrtf(sSs);
    if (t < NX) v[t] /= sn;
    s_last = sn;
    __syncthreads();
  }
  if (t == 0) ws[OFF_STEP] = 0.9f / sqrtf(s_last);
}

// ---------------------------------------------------------------- K5: qC,qD per scenario
__global__ __launch_bounds__(512) void k_buildq(const float* __restrict__ w_err, float* ws) {
  const int s = blockIdx.x;
  const int t = threadIdx.x;
  __shared__ float wsh[NW];
  if (t < NW) wsh[t] = w_err[s*NW + t];
  __syncthreads();
  if (t < NLINE) {
    float wh = 0.f;
    #pragma unroll
    for (int w = 0; w < NW; ++w)
      wh = fmaf(wsh[w], ws[OFF_HWT + w*NLINE + t], wh);
    ws[OFF_QC + s*NLINE + t] = ws[OFF_FUP + t] - wh;
    ws[OFF_QD + s*NLINE + t] = ws[OFF_FDN + t] + wh;
  }
}

// ---------------------------------------------------------------- macro machinery (8 reg cols, col 12 in LDS hx1)
#define ROWKR(M,jp) M(jp,0) M(jp,1) M(jp,2) M(jp,3) M(jp,4) M(jp,5) M(jp,6) M(jp,7)
#define JPLIST(M) M(0) M(1) M(2) M(3) M(4) M(5) M(6) M(7)
#define KLIST(M)  M(0) M(1) M(2) M(3) M(4) M(5) M(6) M(7) M(8) M(9) M(10) M(11) M(12)

#define DECLH(jp,k) unsigned int hr##jp##_##k;
#define DECLROW(jp) ROWKR(DECLH,jp)
#define LDH(jp,k)   hr##jp##_##k = hpu[((((jp)*NUC) + cbase + (k)) << 5) + rg];
#define LDROW(jp)   ROWKR(LDH,jp)

#define ACCD(k)     float acc##k = 0.f;

#ifdef HAVE_FDOT2
#define DOTA(hv, k) acc##k = __builtin_amdgcn_fdot2(h2v(hv), uh2, acc##k, false);
#else
#define DOTA(hv, k) { const unsigned int hcu_ = (hv); \
                      acc##k = fmaf(h2lo(hcu_), uu0, fmaf(h2hi(hcu_), uu1, acc##k)); }
#endif

#define PHA(jp)     { const unsigned int upk_ = u_pk[rg + ((jp) << 5)]; \
                      const half2v uh2 = h2v(upk_); (void)uh2; \
                      const float uu0 = h2lo(upk_), uu1 = h2hi(upk_); \
                      (void)uu0; (void)uu1; \
                      DOTA(hr##jp##_0, 0) DOTA(hr##jp##_1, 1) DOTA(hr##jp##_2, 2) DOTA(hr##jp##_3, 3) \
                      DOTA(hr##jp##_4, 4) DOTA(hr##jp##_5, 5) DOTA(hr##jp##_6, 6) DOTA(hr##jp##_7, 7) \
                      const uint4 q4_ = hx4[((jp) << 9) + t]; \
                      DOTA(q4_.x, 8) DOTA(q4_.y, 9) DOTA(q4_.z, 10) DOTA(q4_.w, 11) \
                      const unsigned int q1_ = hx1[((jp) << 9) + t]; \
                      DOTA(q1_, 12) }

#define TS16(k)     acc##k += __shfl_xor(acc##k, 16);
#define TRED(j)     tv##j += __shfl_xor(tv##j, 8); tv##j += __shfl_xor(tv##j, 4); \
                    tv##j += __shfl_xor(tv##j, 2); tv##j += __shfl_xor(tv##j, 1);

#define BRD(k)      const unsigned int _lo##k = __builtin_amdgcn_readlane(bzu, (k)); \
                    const unsigned int _hi##k = __builtin_amdgcn_readlane(bzu, 32 + (k)); \
                    const float b##k = __uint_as_float((t & 32) ? _hi##k : _lo##k);

#define CMC(hv, k)  { const unsigned int hcu_ = (hv); \
                      fx = fmaf(h2lo(hcu_), b##k, fx); fy = fmaf(h2hi(hcu_), b##k, fy); }
#define PHC(jp)     { float fx = 0.f, fy = 0.f; \
                      CMC(hr##jp##_0, 0) CMC(hr##jp##_1, 1) CMC(hr##jp##_2, 2) CMC(hr##jp##_3, 3) \
                      CMC(hr##jp##_4, 4) CMC(hr##jp##_5, 5) CMC(hr##jp##_6, 6) CMC(hr##jp##_7, 7) \
                      const uint4 q4_ = hx4[((jp) << 9) + t]; \
                      CMC(q4_.x, 8) CMC(q4_.y, 9) CMC(q4_.z, 10) CMC(q4_.w, 11) \
                      const unsigned int q1_ = hx1[((jp) << 9) + t]; \
                      CMC(q1_, 12) \
                      fx += __shfl_xor(fx, 32); fy += __shfl_xor(fy, 32); \
                      if ((t & 32) == 0) fpart2[w][rg + ((jp) << 5)] = make_float2(fx, fy); }

// ---------------------------------------------------------------- K6: PDHG (R10 structure + dot2 only)
__global__ __launch_bounds__(512) void k_pdhg_reg(const float* __restrict__ ws,
                                                  float* __restrict__ out) {
  const int NUCr = ((const int*)(ws + OFF_NUC))[0];
  if (NUCr != NUC) return;

  __shared__ uint4 hx4[8*512];             // cols 8..11, [jp][cg*32+rg] : 64 KB
  __shared__ unsigned int hx1[8*512];      // col 12                    : 16 KB
  __shared__ unsigned int u_pk[256];       // half2 pairs (u[l], u[l+32])
  __shared__ __align__(16) float x_s[512], z_s[512];
  __shared__ float ts[NUC];
  __shared__ __align__(16) float2 fpart2[8][256];
  __shared__ __align__(16) float2 qC2[256], qD2[256], yC2[256], yD2[256];
  __shared__ float yA[NG], yB[NG], qA[NG], qB[NG];
  __shared__ float sYE[1];
  __shared__ int c2u_s[NB], cus_s[NUPAD_MAX + 1], cul_s[NB];

  const int t = threadIdx.x;
  const int s = blockIdx.x;
  const int rg = t & 31, cg = t >> 5, w = t >> 6;
  const int cbase = cg * NC;
  const float step = ws[OFF_STEP];
  const float qE = ws[OFF_QE + s];

  // ---- init
  x_s[t] = 0.f; z_s[t] = 0.f;
  if (t < 256) {
    const int l = (t & 31) + ((t >> 5) << 6);
    const float qc0 = (l < NLINE)      ? ws[OFF_QC + s*NLINE + l]      : 0.f;
    const float qc1 = (l + 32 < NLINE) ? ws[OFF_QC + s*NLINE + l + 32] : 0.f;
    const float qd0 = (l < NLINE)      ? ws[OFF_QD + s*NLINE + l]      : 0.f;
    const float qd1 = (l + 32 < NLINE) ? ws[OFF_QD + s*NLINE + l + 32] : 0.f;
    qC2[t] = make_float2(qc0, qc1); qD2[t] = make_float2(qd0, qd1);
    yC2[t] = make_float2(0.f, 0.f); yD2[t] = make_float2(0.f, 0.f);
    u_pk[t] = 0u;
  }
  if (t < NG) { yA[t] = 0.f; yB[t] = 0.f; qA[t] = ws[OFF_RUP + t]; qB[t] = ws[OFF_RDN + t]; }
  if (t < NB) {
    c2u_s[t] = ((const int*)(ws + OFF_C2U))[t];
    cul_s[t] = ((const int*)(ws + OFF_CUL))[t];
  }
  if (t < NUPAD_MAX + 1) cus_s[t] = ((const int*)(ws + OFF_CUS))[t];
  if (t == 0) sYE[0] = 0.f;

  // ---- load tile: cols 0..7 named regs, cols 8..11 LDS (hx4), col 12 LDS (hx1)
  JPLIST(DECLROW)
  {
    const unsigned int* __restrict__ hpu = (const unsigned int*)(ws + OFF_HSPB);
    JPLIST(LDROW)
    #pragma unroll
    for (int jp = 0; jp < 8; ++jp) {
      hx4[(jp << 9) + t] = make_uint4(
        hpu[((jp*NUC + cbase +  8) << 5) + rg],
        hpu[((jp*NUC + cbase +  9) << 5) + rg],
        hpu[((jp*NUC + cbase + 10) << 5) + rg],
        hpu[((jp*NUC + cbase + 11) << 5) + rg]);
      hx1[(jp << 9) + t] = hpu[((jp*NUC + cbase + 12) << 5) + rg];
    }
  }
  __syncthreads();

  for (int it = 0; it < NITERS; ++it) {
    // ---- Phase A: ts = Hs^T u (dot2), split-tree reduction over 32 lanes
    {
      KLIST(ACCD)
      JPLIST(PHA)
      KLIST(TS16)
      const bool up16 = (t & 16) != 0;
      float tv0 = up16 ? acc7  : acc0;
      float tv1 = up16 ? acc8  : acc1;
      float tv2 = up16 ? acc9  : acc2;
      float tv3 = up16 ? acc10 : acc3;
      float tv4 = up16 ? acc11 : acc4;
      float tv5 = up16 ? acc12 : acc5;
      float tv6 = acc6;
      TRED(0) TRED(1) TRED(2) TRED(3) TRED(4) TRED(5) TRED(6)
      const int jsel = t & 15;
      float wv = tv0;
      wv = (jsel == 1) ? tv1 : wv; wv = (jsel == 2) ? tv2 : wv;
      wv = (jsel == 3) ? tv3 : wv; wv = (jsel == 4) ? tv4 : wv;
      wv = (jsel == 5) ? tv5 : wv; wv = (jsel == 6) ? tv6 : wv;
      const int kout = up16 ? (jsel + 7) : jsel;
      if (up16 ? (jsel < 6) : (jsel < 7)) ts[cbase + kout] = wv;
    }
    __syncthreads();

    // ---- Phase B: x-update
    if (t < NX) {
      const int cc = (t < NB) ? (t % NG) : (t - 200);
      const float tg = ts[c2u_s[cc]];
      const float yE = sYE[0];
      float yK;
      if (t < NG)        yK = yA[t] + tg + yE;
      else if (t < 2*NG) yK = yB[t - NG] - tg - yE;
      else if (t < NB)   yK = -tg - yE;
      else               yK = tg + yE;
      const float cj = (t < 2*NG) ? 0.f : CVIOL;
      const float xo = x_s[t];
      const float x1 = fmaxf(xo - step*(cj + yK), 0.f);
      z_s[t] = 2.f*x1 - xo;
      x_s[t] = x1;
    }
    __syncthreads();

    // ---- Phase C: lane-parallel busz + readlane broadcast, then f partials
    {
      float bz = 0.f;
      if (rg < NC) {
        const int c = cbase + rg;
        const int ke = cus_s[c + 1];
        float a = 0.f;
        for (int kk = cus_s[c]; kk < ke; ++kk) {
          const int comp = cul_s[kk];
          a += (comp < NG) ? (z_s[comp] - z_s[NG + comp] - z_s[2*NG + comp])
                           : z_s[200 + comp];
        }
        bz = a;
      }
      const unsigned int bzu = __float_as_uint(bz);
      KLIST(BRD)
      JPLIST(PHC)
    }
    __syncthreads();

    // ---- Phase D: paired y-update + u; yA/yB; E (wave 7)
    if (t < 256) {
      float2 cv = make_float2(0.f, 0.f);
      #pragma unroll
      for (int g = 0; g < 8; ++g) { const float2 fp = fpart2[g][t]; cv.x += fp.x; cv.y += fp.y; }
      const float2 qc = qC2[t], qd = qD2[t], yc = yC2[t], yd = yD2[t];
      const float cy0 = fmaxf(yc.x + step*( cv.x - qc.x), 0.f);
      const float dy0 = fmaxf(yd.x + step*(-cv.x - qd.x), 0.f);
      const float cy1 = fmaxf(yc.y + step*( cv.y - qc.y), 0.f);
      const float dy1 = fmaxf(yd.y + step*(-cv.y - qd.y), 0.f);
      yC2[t] = make_float2(cy0, cy1); yD2[t] = make_float2(dy0, dy1);
      const unsigned int upk =
          (unsigned int)__half_as_ushort(__float2half(cy0 - dy0)) |
          ((unsigned int)__half_as_ushort(__float2half(cy1 - dy1)) << 16);
      u_pk[t] = upk;
    }
    if (t >= 256 && t < 456) {
      const int g = t - 256;
      if (g < NG) yA[g] = fmaxf(yA[g] + step*(z_s[g] - qA[g]), 0.f);
      else { const int gb = g - NG; yB[gb] = fmaxf(yB[gb] + step*(z_s[g] - qB[gb]), 0.f); }
    }
    if (t >= 448) {
      const int lane = t - 448;
      float e = 0.f;
      #pragma unroll
      for (int m = 0; m < 8; ++m) {
        const int idx = lane + (m << 6);
        const float zv = z_s[idx];                // z_s[500..511] stay 0
        e += (idx < NG || idx >= NB) ? zv : -zv;
      }
      e += __shfl_xor(e, 32); e += __shfl_xor(e, 16); e += __shfl_xor(e, 8);
      e += __shfl_xor(e, 4);  e += __shfl_xor(e, 2);  e += __shfl_xor(e, 1);
      if (t == 511) sYE[0] += step*(e - qE);
    }
    __syncthreads();
  }

  // ---- cost = CVIOL * sum(x[200:500])
  if (t < 64) {
    float p = 0.f;
    for (int k = 200 + t; k < NX; k += 64) p += x_s[k];
    for (int o = 32; o; o >>= 1) p += __shfl_down(p, o);
    if (t == 0) out[s] = CVIOL * p;
  }
}

// ---------------------------------------------------------------- K6fb: streaming fallback (NU > 208)
__global__ __launch_bounds__(1024) void k_pdhg_fb(const float* __restrict__ ws,
                                                  float* __restrict__ out) {
  const int NUCr = ((const int*)(ws + OFF_NUC))[0];
  if (NUCr != 0) return;
  const int NUPr = ((const int*)(ws + OFF_NUP))[0];

  __shared__ float u_s[512], x_s[512], z_s[512], cv_s[512];
  __shared__ float ts[NUPAD_MAX], busz[NUPAD_MAX];
  __shared__ float yC[NLINE], yD[NLINE], qC[NLINE], qD[NLINE];
  __shared__ float yA[NG], yB[NG], qA[NG], qB[NG];
  __shared__ float sE[1], sYE[1];
  __shared__ int c2u_s[NB], cus_s[NUPAD_MAX + 1], cul_s[NB];

  const int t = threadIdx.x;
  const int s = blockIdx.x;
  const float step = ws[OFF_STEP];
  const float qE = ws[OFF_QE + s];
  const float* __restrict__ HST = ws + OFF_HST;

  if (t < 512) { u_s[t] = 0.f; x_s[t] = 0.f; z_s[t] = 0.f; }
  if (t < NLINE) {
    yC[t] = 0.f; yD[t] = 0.f;
    qC[t] = ws[OFF_QC + s*NLINE + t];
    qD[t] = ws[OFF_QD + s*NLINE + t];
  }
  if (t < NG) { yA[t] = 0.f; yB[t] = 0.f; qA[t] = ws[OFF_RUP + t]; qB[t] = ws[OFF_RDN + t]; }
  if (t < NB) {
    c2u_s[t] = ((const int*)(ws + OFF_C2U))[t];
    cul_s[t] = ((const int*)(ws + OFF_CUL))[t];
  }
  if (t < NUPAD_MAX + 1) cus_s[t] = ((const int*)(ws + OFF_CUS))[t];
  if (t == 0) { sE[0] = 0.f; sYE[0] = 0.f; }
  __syncthreads();

  const int w = t >> 6, lane = t & 63;

  for (int it = 0; it < NITERS; ++it) {
    for (int c = w; c < NUPr; c += 16) {
      float a = 0.f;
      #pragma unroll
      for (int m = 0; m < 8; ++m) { const int l = lane + (m << 6); a = fmaf(HST[c*512 + l], u_s[l], a); }
      a += __shfl_xor(a, 32); a += __shfl_xor(a, 16); a += __shfl_xor(a, 8);
      a += __shfl_xor(a, 4);  a += __shfl_xor(a, 2);  a += __shfl_xor(a, 1);
      if (lane == 0) ts[c] = a;
    }
    __syncthreads();
    if (t < NX) {
      const int cc = (t < NB) ? (t % NG) : (t - 200);
      const float tg = ts[c2u_s[cc]];
      const float yE = sYE[0];
      float yK;
      if (t < NG)        yK = yA[t] + tg + yE;
      else if (t < 2*NG) yK = yB[t - NG] - tg - yE;
      else if (t < NB)   yK = -tg - yE;
      else               yK = tg + yE;
      const float cj = (t < 2*NG) ? 0.f : CVIOL;
      const float xo = x_s[t];
      const float x1 = fmaxf(xo - step*(cj + yK), 0.f);
      z_s[t] = 2.f*x1 - xo;
      x_s[t] = x1;
    }
    __syncthreads();
    if (t < NUPr) {
      float a = 0.f;
      const int k0 = cus_s[t], k1 = cus_s[t + 1];
      for (int k = k0; k < k1; ++k) {
        const int c = cul_s[k];
        a += (c < NG) ? (z_s[c] - z_s[NG + c] - z_s[2*NG + c]) : z_s[200 + c];
      }
      busz[t] = a;
    } else if (t >= 768 && t < 832) {
      const int ln = t - 768;
      float e = 0.f;
      for (int idx = ln; idx < NX; idx += 64) {
        const float zv = z_s[idx];
        e += (idx < NG || idx >= NB) ? zv : -zv;
      }
      e += __shfl_xor(e, 32); e += __shfl_xor(e, 16); e += __shfl_xor(e, 8);
      e += __shfl_xor(e, 4);  e += __shfl_xor(e, 2);  e += __shfl_xor(e, 1);
      if (ln == 0) sE[0] = e;
    }
    __syncthreads();
    if (t < 512) {
      float a = 0.f;
      for (int c = 0; c < NUPr; ++c) a = fmaf(HST[c*512 + t], busz[c], a);
      cv_s[t] = a;
    }
    __syncthreads();
    if (t < NLINE) {
      const float cv = cv_s[t];
      const float cy = fmaxf(yC[t] + step*( cv - qC[t]), 0.f);
      const float dy = fmaxf(yD[t] + step*(-cv - qD[t]), 0.f);
      yC[t] = cy; yD[t] = dy; u_s[t] = cy - dy;
    } else if (t >= 512 && t < 612) {
      const int g = t - 512;
      yA[g] = fmaxf(yA[g] + step*(z_s[g] - qA[g]), 0.f);
    } else if (t >= 612 && t < 712) {
      const int g = t - 612;
      yB[g] = fmaxf(yB[g] + step*(z_s[NG + g] - qB[g]), 0.f);
    } else if (t == 1023) {
      sYE[0] += step*(sE[0] - qE);
    }
    __syncthreads();
  }
  if (t < 64) {
    float p = 0.f;
    for (int k = 200 + t; k < NX; k += 64) p += x_s[k];
    for (int o = 32; o; o >>= 1) p += __shfl_down(p, o);
    if (t == 0) out[s] = CVIOL * p;
  }
}

extern "C" void kernel_launch(void* const* d_in, const int* in_sizes, int n_in,
                              void* d_out, int out_size, void* d_ws, size_t ws_size,
                              hipStream_t stream) {
  (void)in_sizes; (void)n_in; (void)out_size; (void)ws_size;
  const float* p_da      = (const float*)d_in[0];
  const float* r_up_hat  = (const float*)d_in[1];
  const float* r_dn_hat  = (const float*)d_in[2];
  const float* fup_hat   = (const float*)d_in[3];
  const float* fdn_hat   = (const float*)d_in[4];
  const float* w_err     = (const float*)d_in[5];
  const float* Pmax      = (const float*)d_in[6];
  const float* PTDF      = (const float*)d_in[7];
  const float* nG        = (const float*)d_in[8];
  const float* nL        = (const float*)d_in[9];
  const float* nW        = (const float*)d_in[10];
  float* ws  = (float*)d_ws;
  float* out = (float*)d_out;

  hipLaunchKernelGGL(k_pre,    dim3(1),   dim3(512),  0, stream,
                     p_da, r_up_hat, r_dn_hat, fup_hat, fdn_hat, w_err, Pmax, nG, nL, nW, ws);
  hipLaunchKernelGGL(k_buildH, dim3(500), dim3(512),  0, stream, PTDF, ws);
  hipLaunchKernelGGL(k_buildB, dim3(304), dim3(192),  0, stream, ws);
  hipLaunchKernelGGL(k_power,  dim3(1),   dim3(512),  0, stream, ws);
  hipLaunchKernelGGL(k_buildq, dim3(128), dim3(512),  0, stream, w_err, ws);
  hipLaunchKernelGGL(k_pdhg_reg, dim3(128), dim3(512), 0, stream, ws, out);
  hipLaunchKernelGGL(k_pdhg_fb, dim3(128), dim3(1024), 0, stream, ws, out);
}